// Round 7
// baseline (141.535 us; speedup 1.0000x reference)
//
#include <hip/hip_runtime.h>
#include <math.h>

#define NN 1024
#define KK 256
#define NH 4
#define FD 64
#define HF 256

typedef __attribute__((ext_vector_type(16))) float fx16;

// ---- workspace float offsets ----
#define OFF_GL   0
#define OFF_GR   (256*1024)
#define OFF_CL   (512*1024)
#define OFF_CR   (512*1024 + 4096)
#define OFF_DENP (512*1024 + 8192)          // 32 chunks x 4096
#define OFF_ACCP (768*1024)                 // 32 chunks x 256K floats (32MB)

// ---------------- GEMM: G = A @ W, cl/cr fused, no atomics ----------------
// W redundancy across m-groups is L1-served (drift << 32KB window): ~4-5us.
__global__ __launch_bounds__(256) void gatv2_gemm(
    const float* __restrict__ hmat, const float* __restrict__ nei,
    const float* __restrict__ w_l, const float* __restrict__ w_r,
    const float* __restrict__ aw, float* __restrict__ ws)
{
    __shared__ float sA[16*260];
    const int t   = threadIdx.x;
    const int mb  = blockIdx.x;
    const int hd  = blockIdx.y;
    const int mat = blockIdx.z;
    const float* A = mat ? nei : hmat;
    const float* W = mat ? w_r : w_l;
    float* G  = ws + (mat ? OFF_GR : OFF_GL);
    float* CC = ws + (mat ? OFF_CR : OFF_CL);

    #pragma unroll
    for (int rep = 0; rep < 4; ++rep) {
        const int flat = rep*256 + t;
        const int r = flat >> 6, c = (flat & 63) << 2;
        *(float4*)&sA[r*260 + c] = *(const float4*)&A[(size_t)(mb*16 + r)*KK + c];
    }
    __syncthreads();

    const int m  = t >> 4;
    const int nq = t & 15;
    const int ng = hd*64 + (nq << 2);
    const float* Wp = W + ng;

    float4 acc = make_float4(0.f, 0.f, 0.f, 0.f);
    #pragma unroll 4
    for (int k0 = 0; k0 < KK; k0 += 4) {
        const float4 a4 = *(const float4*)&sA[m*260 + k0];
        const float4 w0 = *(const float4*)(Wp + (size_t)(k0+0)*HF);
        const float4 w1 = *(const float4*)(Wp + (size_t)(k0+1)*HF);
        const float4 w2 = *(const float4*)(Wp + (size_t)(k0+2)*HF);
        const float4 w3 = *(const float4*)(Wp + (size_t)(k0+3)*HF);
        acc.x += a4.x*w0.x; acc.y += a4.x*w0.y; acc.z += a4.x*w0.z; acc.w += a4.x*w0.w;
        acc.x += a4.y*w1.x; acc.y += a4.y*w1.y; acc.z += a4.y*w1.z; acc.w += a4.y*w1.w;
        acc.x += a4.z*w2.x; acc.y += a4.z*w2.y; acc.z += a4.z*w2.z; acc.w += a4.z*w2.w;
        acc.x += a4.w*w3.x; acc.y += a4.w*w3.y; acc.z += a4.w*w3.z; acc.w += a4.w*w3.w;
    }

    *(float4*)&G[(size_t)(mb*16 + m)*HF + ng] = acc;

    {
        const float4 w4 = ((const float4*)aw)[nq];
        float wd = w4.x*acc.x + w4.y*acc.y + w4.z*acc.z + w4.w*acc.w;
        wd += __shfl_xor(wd, 1);
        wd += __shfl_xor(wd, 2);
        wd += __shfl_xor(wd, 4);
        wd += __shfl_xor(wd, 8);
        if (nq == 0) CC[hd*NN + mb*16 + m] = 0.6f*wd;
    }
}

// ---------------- Fused attention: e + exp + PV accumulate ----------------
// Thread owns (i, h). Per j: g_l row -> 64 SGPRs (s_load_dwordx16 x4 + cl,
// wait inside asm), e-compute (v_add + v_fma-abs); then g_r row into the
// SAME 64 SGPRs (WAR on C vars orders the asm blocks), acc += pw*row
// (v_fma with SGPR operand). P never materialized. ~412 VALU-cyc per j vs
// ~400 SMEM-stall -> 2 waves/SIMD interleave complementarily.
#define EBLK(RV, QB)                                                \
    { _Pragma("unroll") for (int q = 0; q < 4; ++q) {               \
        const float4 wq = w[(QB)+q]; const float4 gq = gri[(QB)+q]; \
        e0 += wq.x * fabsf(RV[q*4+0] + gq.x);                       \
        e1 += wq.y * fabsf(RV[q*4+1] + gq.y);                       \
        e2 += wq.z * fabsf(RV[q*4+2] + gq.z);                       \
        e3 += wq.w * fabsf(RV[q*4+3] + gq.w); } }

#define PVACC(RV, QB)                                               \
    { _Pragma("unroll") for (int q = 0; q < 4; ++q) {               \
        acc[(QB)+q].x += pw*RV[q*4+0];                              \
        acc[(QB)+q].y += pw*RV[q*4+1];                              \
        acc[(QB)+q].z += pw*RV[q*4+2];                              \
        acc[(QB)+q].w += pw*RV[q*4+3]; } }

__global__ __launch_bounds__(256, 2) void gatv2_attn(
    const float* __restrict__ wsro, const float* __restrict__ adj,
    const float* __restrict__ aw,
    float* __restrict__ accP, float* __restrict__ denP)
{
    __shared__ float s_w[64];
    const float* g_l = wsro + OFF_GL;
    const float* g_r = wsro + OFF_GR;
    const float* cl  = wsro + OFF_CL;
    const float* cr  = wsro + OFF_CR;
    const int t  = threadIdx.x;
    const int jc = blockIdx.x;   // 32 j-chunks of 32
    const int ib = blockIdx.y;   // 4
    const int hh = blockIdx.z;   // 4
    const int i  = ib*256 + t;

    if (t < 16) ((float4*)s_w)[t] = ((const float4*)aw)[t];
    __syncthreads();

    float4 w[16], gri[16];
    {
        const float4* gp = (const float4*)(g_r + (size_t)i*HF + hh*FD);
        #pragma unroll
        for (int q = 0; q < 16; ++q) {
            w[q]   = ((const float4*)s_w)[q];   // ds_read -> per-lane VGPRs
            gri[q] = gp[q];
        }
    }
    const float cri = cr[hh*NN + i];

    float4 acc[16];
    #pragma unroll
    for (int q = 0; q < 16; ++q) acc[q] = make_float4(0.f,0.f,0.f,0.f);
    float denl = 0.f;

    const int j0 = jc*32;
    float mask_next = adj[(size_t)j0*NN + i];
    for (int jj = 0; jj < 32; ++jj) {
        const int j = j0 + jj;
        const float mask = mask_next;
        if (jj + 1 < 32) mask_next = adj[(size_t)(j + 1)*NN + i];

        fx16 r0, r1, r2, r3; float clv;
        {   // g_l row + cl -> SGPRs
            const float* rowp = g_l + (size_t)j*HF + hh*FD;
            const float* clp  = cl + hh*NN + j;
            asm volatile(
                "s_load_dwordx16 %0, %5, 0x0\n\t"
                "s_load_dwordx16 %1, %5, 0x40\n\t"
                "s_load_dwordx16 %2, %5, 0x80\n\t"
                "s_load_dwordx16 %3, %5, 0xc0\n\t"
                "s_load_dword %4, %6, 0x0\n\t"
                "s_waitcnt lgkmcnt(0)"
                : "=s"(r0), "=s"(r1), "=s"(r2), "=s"(r3), "=s"(clv)
                : "s"(rowp), "s"(clp));
        }
        float e0 = 0.f, e1 = 0.f, e2 = 0.f, e3 = 0.f;
        EBLK(r0, 0) EBLK(r1, 4) EBLK(r2, 8) EBLK(r3, 12)
        const float e  = cri + clv + 0.4f*((e0+e1)+(e2+e3));
        const float pw = (mask != 0.f) ? __expf(e) : 0.f;
        denl += pw;

        {   // g_r row -> same SGPR buffers (WAR-ordered after EBLK reads)
            const float* rowp = g_r + (size_t)j*HF + hh*FD;
            asm volatile(
                "s_load_dwordx16 %0, %4, 0x0\n\t"
                "s_load_dwordx16 %1, %4, 0x40\n\t"
                "s_load_dwordx16 %2, %4, 0x80\n\t"
                "s_load_dwordx16 %3, %4, 0xc0\n\t"
                "s_waitcnt lgkmcnt(0)"
                : "=s"(r0), "=s"(r1), "=s"(r2), "=s"(r3)
                : "s"(rowp));
        }
        PVACC(r0, 0) PVACC(r1, 4) PVACC(r2, 8) PVACC(r3, 12)
    }

    // store partial acc in out-layout: accP[jc][(i*NH+hh)*FD + f]
    float* op = accP + (size_t)jc*(NN*HF) + ((size_t)i*NH + hh)*FD;
    #pragma unroll
    for (int q = 0; q < 16; ++q) ((float4*)op)[q] = acc[q];
    denP[(size_t)jc*(NN*NH) + hh*NN + i] = denl;
}

// ---------------- Final: sum partials, /den, elu ----------------
__global__ __launch_bounds__(256) void gatv2_fin(
    const float* __restrict__ accP, const float* __restrict__ denP,
    const int* __restrict__ use_elu, float* __restrict__ out)
{
    const int idx4 = blockIdx.x*256 + threadIdx.x;  // float4 index over out
    const int i  = idx4 >> 6;
    const int hh = (idx4 >> 4) & 3;
    float4 s = make_float4(0.f,0.f,0.f,0.f);
    for (int c = 0; c < 32; ++c) {
        const float4 v = *(const float4*)&accP[(size_t)c*(NN*HF) + (size_t)idx4*4];
        s.x += v.x; s.y += v.y; s.z += v.z; s.w += v.w;
    }
    float d = 0.f;
    for (int c = 0; c < 32; ++c) d += denP[(size_t)c*(NN*NH) + hh*NN + i];
    const float rd = 1.f / d;
    float4 r = make_float4(s.x*rd, s.y*rd, s.z*rd, s.w*rd);
    if (*use_elu != 0) {
        r.x = (r.x > 0.f) ? r.x : expm1f(r.x);
        r.y = (r.y > 0.f) ? r.y : expm1f(r.y);
        r.z = (r.z > 0.f) ? r.z : expm1f(r.z);
        r.w = (r.w > 0.f) ? r.w : expm1f(r.w);
    }
    ((float4*)out)[idx4] = r;
}

extern "C" void kernel_launch(void* const* d_in, const int* in_sizes, int n_in,
                              void* d_out, int out_size, void* d_ws, size_t ws_size,
                              hipStream_t stream)
{
    const float* hmat = (const float*)d_in[0];
    const float* nei  = (const float*)d_in[1];
    const float* adj  = (const float*)d_in[2];
    const float* w_l  = (const float*)d_in[3];
    const float* w_r  = (const float*)d_in[4];
    const float* aw   = (const float*)d_in[5];
    const int*   uel  = (const int*)d_in[6];
    float* out = (float*)d_out;
    float* ws  = (float*)d_ws;

    hipLaunchKernelGGL(gatv2_gemm, dim3(64,4,2), dim3(256), 0, stream,
                       hmat, nei, w_l, w_r, aw, ws);
    hipLaunchKernelGGL(gatv2_attn, dim3(32,4,4), dim3(256), 0, stream,
                       ws, adj, aw, ws + OFF_ACCP, ws + OFF_DENP);
    hipLaunchKernelGGL(gatv2_fin, dim3((NN*HF)/1024), dim3(256), 0, stream,
                       ws + OFF_ACCP, ws + OFF_DENP, uel, out);
}